// Round 4
// baseline (986.903 us; speedup 1.0000x reference)
//
#include <hip/hip_runtime.h>
#include <cstdint>

#define VOCAB 500000
#define STEPS 64
#define EPSF 1e-8f

__device__ __forceinline__ float sigm(float x) { return 1.f / (1.f + expf(-x)); }
__device__ __forceinline__ float dot4(float4 a, float4 b) {
    return a.x * b.x + a.y * b.y + a.z * b.z + a.w * b.w;
}
__device__ __forceinline__ unsigned long long ullmax(unsigned long long a, unsigned long long b) {
    return a > b ? a : b;
}
// order-preserving float->uint32 map (monotone increasing)
__device__ __forceinline__ unsigned fmap(float f) {
    unsigned u = __float_as_uint(f);
    return (u & 0x80000000u) ? ~u : (u | 0x80000000u);
}

// ---------------- Kernel A: 64-step LSTM recurrence (single block, 1024 threads) ----------------
// Thread t owns HALF a gate row: r = t&511, hf = t>>9 selects cols [hf*128, hf*128+128) of [x;h].
//   hf=0 -> A row   = w_ih[r][0:128]   (multiplies x = c_prev)
//   hf=1 -> U row   = w_hh[r][0:128]   (multiplies h)
// Per-thread weights: 24 float4 in registers (96 VGPR, fits the 128-reg budget the
// allocator actually grants — R2/R3 proved it spills anything larger) + 8 float4 in LDS
// (1024*8*16B = 128 KB, rotate-swizzled (j+t)&7 so each b128 read covers all 32 banks).
// Halves reduce through part[1024]; activations by threads t<128 via kvs[] + part[].
__global__ __launch_bounds__(1024)
void lstm_kernel(
    const float* __restrict__ inp, const float* __restrict__ embed,
    const float* __restrict__ w_ih, const float* __restrict__ w_hh,
    const float* __restrict__ b_ih, const float* __restrict__ b_hh,
    float* __restrict__ out_cs,                 // d_out[0 .. 64*128)
    unsigned long long* __restrict__ slots)     // ws: 64 argmax slots
{
    __shared__ float4 wlds[1024 * 8];   // 128 KB weight tails
    __shared__ float vv[256];           // [x(128) ; h(128)]
    __shared__ float part[1024];        // per-thread half-row partial sums
    __shared__ float kvs[512];          // bias + w_ih[:,128:256] @ inp (step-constant)

    const int t = threadIdx.x;
    const int r = t & 511;
    const int hf = t >> 9;

    if (t < STEPS) slots[t] = 0ull;   // vocab kernel is stream-ordered after us

    const float4* wrow = (hf == 0) ? (const float4*)(w_ih + (size_t)r * 256)
                                   : (const float4*)(w_hh + (size_t)r * 128);

    // LDS weight tail: cols j4=24..31 of this thread's half-row, rotate-swizzled
    for (int j = 0; j < 8; ++j)
        wlds[t * 8 + ((j + t) & 7)] = wrow[24 + j];

    // register-resident weight head (full unroll: constant indices keep wreg in VGPRs)
    float4 wreg[24];
#pragma unroll
    for (int j = 0; j < 24; ++j) wreg[j] = wrow[j];

    // kv[r] = b_ih + b_hh + w_ih[r][128:256] . inp  (constant across steps)
    if (hf == 0) {
        float kv = b_ih[r] + b_hh[r];
        const float4* wib = (const float4*)(w_ih + (size_t)r * 256) + 32;
        const float4* inp4 = (const float4*)inp;
        float k0 = 0.f, k1 = 0.f;
#pragma unroll
        for (int j = 0; j < 32; j += 2) {
            k0 += dot4(wib[j], inp4[j]);
            k1 += dot4(wib[j + 1], inp4[j + 1]);
        }
        kvs[r] = kv + k0 + k1;
    }

    if (t < 128) { vv[t] = embed[t]; vv[128 + t] = 0.f; }  // x0 = embed[0], h0 = 0
    float creg = 0.f;
    __syncthreads();

    const int base = hf * 32;   // float4 offset into vv for this half
    const int wb = t * 8;
    for (int st = 0; st < STEPS; ++st) {
        const float4* v4 = (const float4*)vv;
        float a0 = 0.f, a1 = 0.f;
#pragma unroll
        for (int j = 0; j < 24; j += 2) {          // register weights (broadcast vv reads)
            a0 += dot4(wreg[j],     v4[base + j]);
            a1 += dot4(wreg[j + 1], v4[base + j + 1]);
        }
#pragma unroll
        for (int j = 0; j < 8; ++j) {              // LDS weight tail
            float4 w = wlds[wb + ((j + t) & 7)];
            a0 += dot4(w, v4[base + 24 + j]);
        }
        part[t] = a0 + a1;
        __syncthreads();
        if (t < 128) {
            float gi = kvs[t]       + part[t]       + part[512 + t];
            float gf = kvs[128 + t] + part[128 + t] + part[640 + t];
            float gg = kvs[256 + t] + part[256 + t] + part[768 + t];
            float go = kvs[384 + t] + part[384 + t] + part[896 + t];
            float ig = sigm(gi), fg = sigm(gf), g2 = tanhf(gg), og = sigm(go);
            float cn = fg * creg + ig * g2;
            float hn = og * tanhf(cn);
            creg = cn;
            vv[t] = cn;            // next x = c_new
            vv[128 + t] = hn;      // next h
            out_cs[st * 128 + t] = cn;
        }
        __syncthreads();
    }
}

// ---------------- Kernel B: one pass over embed, 64 dots/row + norm + argmax ----------------
// 256 threads, 256 rows/block (4 tiles of 64), software-pipelined: next tile prefetched into
// 32 VGPRs while computing the current one (hides ~900-cyc HBM latency at 8 waves/CU).
__global__ __launch_bounds__(256)
void vocab_kernel(
    const float* __restrict__ embed,
    const float* __restrict__ cs,               // d_out[0..8192): [64][128] c vectors
    unsigned long long* __restrict__ slots)
{
    __shared__ float4 c_lds[64 * 32];   // 32 KB, swizzled [t][j4 ^ (t&31)]
    __shared__ float4 e_lds[64 * 32];   // 32 KB, swizzled; reused as u64 reduction scratch
    __shared__ float ssq_part[64 * 32]; // 8 KB: per-(row,j4) |e4|^2 partials

    const int tid = threadIdx.x;
    const int tx = tid & 15, ry = tid >> 4;

    // stage c matrix once (swizzled)
    const float4* cs4 = (const float4*)cs;
#pragma unroll 2
    for (int k = 0; k < 8; ++k) {
        int f = tid + k * 256;
        int row = f >> 5, j4 = f & 31;
        c_lds[row * 32 + (j4 ^ (row & 31))] = cs4[f];
    }

    unsigned long long running = 0ull;   // tid<64: best key for t = tid
    const long long blockbase = (long long)blockIdx.x * 256;
    const float4* embed4 = (const float4*)embed;

    int Pe[4], Pc[4];
#pragma unroll
    for (int rr = 0; rr < 4; ++rr) { int row = ry + 16 * rr; Pe[rr] = row * 32 + (row & 31); }
#pragma unroll
    for (int tt = 0; tt < 4; ++tt) { int t = tx + 16 * tt; Pc[tt] = t * 32 + (t & 31); }

    // prologue: prefetch tile 0 into registers
    float4 pf[8];
#pragma unroll
    for (int k = 0; k < 8; ++k) {
        int f = tid + k * 256;
        long long grow = blockbase + (f >> 5);
        pf[k] = make_float4(0.f, 0.f, 0.f, 0.f);
        if (grow < VOCAB) pf[k] = embed4[grow * 32 + (f & 31)];
    }

    for (int tile = 0; tile < 4; ++tile) {
        const long long rowbase = blockbase + tile * 64;
        __syncthreads();   // prev reduction reads done before restaging e_lds / ssq_part

        // stage prefetched tile (vmcnt wait happens here, one full tile of latency ago)
#pragma unroll
        for (int k = 0; k < 8; ++k) {
            int f = tid + k * 256;
            int row = f >> 5, j4 = f & 31;
            e_lds[row * 32 + (j4 ^ (row & 31))] = pf[k];
            ssq_part[row * 32 + j4] = dot4(pf[k], pf[k]);
        }

        // fire next tile's global loads — in flight across the whole compute phase
        if (tile < 3) {
            const long long nextbase = rowbase + 64;
#pragma unroll
            for (int k = 0; k < 8; ++k) {
                int f = tid + k * 256;
                long long grow = nextbase + (f >> 5);
                pf[k] = make_float4(0.f, 0.f, 0.f, 0.f);
                if (grow < VOCAB) pf[k] = embed4[grow * 32 + (f & 31)];
            }
        }
        __syncthreads();

        float acc[4][4];
#pragma unroll
        for (int rr = 0; rr < 4; ++rr)
#pragma unroll
            for (int tt = 0; tt < 4; ++tt) acc[rr][tt] = 0.f;

#pragma unroll 2
        for (int j4 = 0; j4 < 32; ++j4) {
            float4 c0 = c_lds[Pc[0] ^ j4];
            float4 c1 = c_lds[Pc[1] ^ j4];
            float4 c2 = c_lds[Pc[2] ^ j4];
            float4 c3 = c_lds[Pc[3] ^ j4];
#pragma unroll
            for (int rr = 0; rr < 4; ++rr) {
                float4 e = e_lds[Pe[rr] ^ j4];
                acc[rr][0] += dot4(e, c0);
                acc[rr][1] += dot4(e, c1);
                acc[rr][2] += dot4(e, c2);
                acc[rr][3] += dot4(e, c3);
            }
        }

        // per-row inv-norm from staged partials (broadcast reads, once per tile)
        float inv[4];
        long long grows[4];
#pragma unroll
        for (int rr = 0; rr < 4; ++rr) {
            int row = ry + 16 * rr;
            float s0 = 0.f, s1 = 0.f;
#pragma unroll 4
            for (int j = 0; j < 32; j += 2) {
                s0 += ssq_part[row * 32 + j];
                s1 += ssq_part[row * 32 + j + 1];
            }
            inv[rr] = 1.f / fmaxf(sqrtf(s0 + s1), EPSF);
            grows[rr] = rowbase + row;
        }
        __syncthreads();   // all e_lds reads done; safe to reuse as scratch

        unsigned long long* red = (unsigned long long*)e_lds;  // [tt*256 + tx*16 + ry]
#pragma unroll
        for (int tt = 0; tt < 4; ++tt) {
            unsigned long long k = 0ull;
#pragma unroll
            for (int rr = 0; rr < 4; ++rr) {
                if (grows[rr] < VOCAB) {
                    float q = acc[rr][tt] * inv[rr];
                    unsigned long long key = ((unsigned long long)fmap(q) << 32)
                                           | (unsigned)(0x7FFFFFFF - (int)grows[rr]);
                    k = ullmax(k, key);
                }
            }
            red[tt * 256 + tx * 16 + ry] = k;
        }
        __syncthreads();

        if (tid < 64) {
            int t = tid, ttx = t & 15, ttt = t >> 4;
#pragma unroll
            for (int r2 = 0; r2 < 16; ++r2)
                running = ullmax(running, red[ttt * 256 + ttx * 16 + r2]);
        }
    }

    if (tid < 64) atomicMax(&slots[tid], running);
}

// ---------------- Kernel C: decode argmax slots to float indices ----------------
__global__ void finalize_kernel(const unsigned long long* __restrict__ slots,
                                float* __restrict__ out_dec)
{
    int t = threadIdx.x;
    if (t < STEPS) {
        unsigned idx = 0x7FFFFFFFu - (unsigned)(slots[t] & 0xFFFFFFFFu);
        out_dec[t] = (float)idx;
    }
}

extern "C" void kernel_launch(void* const* d_in, const int* in_sizes, int n_in,
                              void* d_out, int out_size, void* d_ws, size_t ws_size,
                              hipStream_t stream) {
    (void)in_sizes; (void)n_in; (void)out_size; (void)ws_size;
    const float* inp   = (const float*)d_in[0];
    const float* embed = (const float*)d_in[1];
    const float* w_ih  = (const float*)d_in[2];
    const float* w_hh  = (const float*)d_in[3];
    const float* b_ih  = (const float*)d_in[4];
    const float* b_hh  = (const float*)d_in[5];
    float* out = (float*)d_out;
    unsigned long long* slots = (unsigned long long*)d_ws;

    hipLaunchKernelGGL(lstm_kernel, dim3(1), dim3(1024), 0, stream,
                       inp, embed, w_ih, w_hh, b_ih, b_hh, out, slots);
    const int nblocks = (VOCAB + 255) / 256;   // 1954
    hipLaunchKernelGGL(vocab_kernel, dim3(nblocks), dim3(256), 0, stream,
                       embed, out, slots);
    hipLaunchKernelGGL(finalize_kernel, dim3(1), dim3(64), 0, stream,
                       slots, out + STEPS * 128);
}